// Round 1
// baseline (598.279 us; speedup 1.0000x reference)
//
#include <hip/hip_runtime.h>

#define Bn   32
#define Cn   512
#define GCn  128
#define HWn  3136

#define Q_ELEMS  (Bn*GCn*HWn)     // 12845056
#define KV_ELEMS (Bn*4*32*32)     // 131072
#define KS_ELEMS (Bn*4*32)        // 4096

__device__ __forceinline__ float act_elu1(float v) {
    return v > 0.0f ? v + 1.0f : __expf(v);
}

// ---- transpose w_qk (256x128) -> wt (128x256) so pass-1 staging is coalesced ----
__global__ void k_wt(const float* __restrict__ w_qk, float* __restrict__ wt) {
    int idx = blockIdx.x * 256 + threadIdx.x;   // 32768 total
    int c = idx >> 8, o = idx & 255;
    wt[idx] = w_qk[o * 128 + c];
}

// ---- mem = x[:, :128] copy, float4 ----
__global__ void k_copy(const float* __restrict__ x, float* __restrict__ out) {
    long long idx4 = (long long)blockIdx.x * 256 + threadIdx.x;  // < 3211264
    int b = (int)(idx4 / 100352);       // 128*784 float4 per batch chunk
    int r = (int)(idx4 % 100352);
    ((float4*)out)[idx4] = ((const float4*)x)[(long long)b * 401408 + r];
}

// ---- qk 1x1-conv GEMM: out 256 rows x 64 cols per block, BK=32, 8x8/thread ----
// writes elu(qk)+1: rows 0..127 -> q_ws, rows 128..255 -> k_ws  (layout [b][row][n])
__global__ __launch_bounds__(256) void k_qkgemm(
    const float* __restrict__ x, const float* __restrict__ wt,
    const float* __restrict__ b_qk,
    float* __restrict__ q_ws, float* __restrict__ k_ws) {

    __shared__ __align__(16) float A_lds[32*68];     // [c][64 +pad]
    __shared__ __align__(16) float Wt_lds[32*264];   // [c][256+pad]

    const int t  = threadIdx.x;
    const int n0 = blockIdx.x * 64;
    const int b  = blockIdx.y;
    const int ox = t >> 3;      // 0..31  (8 output rows each)
    const int jx = t & 7;       // 0..7   (8 output cols each)

    const float* Ab = x + ((long long)(b*Cn + GCn))*HWn + n0;  // feat_att base

    float acc[8][8];
    #pragma unroll
    for (int i = 0; i < 8; ++i)
        #pragma unroll
        for (int j = 0; j < 8; ++j) acc[i][j] = 0.f;

    for (int cc = 0; cc < 4; ++cc) {
        #pragma unroll
        for (int l = 0; l < 2; ++l) {               // A chunk: 512 float4
            int idx4 = t + l*256;
            int c = idx4 >> 4, j4 = idx4 & 15;
            *(float4*)(A_lds + c*68 + j4*4) =
                *(const float4*)(Ab + (long long)(cc*32 + c)*HWn + j4*4);
        }
        #pragma unroll
        for (int l = 0; l < 8; ++l) {               // Wt chunk: 2048 float4
            int idx4 = t + l*256;
            int c = idx4 >> 6, o4 = idx4 & 63;
            *(float4*)(Wt_lds + c*264 + o4*4) =
                *(const float4*)(wt + (cc*32 + c)*256 + o4*4);
        }
        __syncthreads();
        #pragma unroll
        for (int c = 0; c < 32; ++c) {
            float a[8], w[8];
            *(float4*)(a)   = *(const float4*)(A_lds + c*68 + jx*8);
            *(float4*)(a+4) = *(const float4*)(A_lds + c*68 + jx*8 + 4);
            *(float4*)(w)   = *(const float4*)(Wt_lds + c*264 + ox*8);
            *(float4*)(w+4) = *(const float4*)(Wt_lds + c*264 + ox*8 + 4);
            #pragma unroll
            for (int i = 0; i < 8; ++i)
                #pragma unroll
                for (int j = 0; j < 8; ++j)
                    acc[i][j] = __builtin_fmaf(w[i], a[j], acc[i][j]);
        }
        __syncthreads();
    }

    float* dst_base = (ox < 16) ? q_ws : k_ws;
    const int row0 = (ox < 16) ? ox*8 : (ox-16)*8;
    #pragma unroll
    for (int i = 0; i < 8; ++i) {
        const int o = ox*8 + i;                 // global W row 0..255
        const float bias = b_qk[o];
        float v[8];
        #pragma unroll
        for (int j = 0; j < 8; ++j) v[j] = act_elu1(acc[i][j] + bias);
        float* dst = dst_base + ((long long)(b*GCn + row0 + i))*HWn + n0 + jx*8;
        *(float4*)dst     = *(float4*)v;
        *(float4*)(dst+4) = *(float4*)(v+4);
    }
}

// ---- kv[d][e] = sum_n k[n,d]*v[n,e] ; ksum[d] = sum_n k[n,d]  (partials via atomics) ----
__global__ __launch_bounds__(256) void k_kv(
    const float* __restrict__ x, const float* __restrict__ k_ws,
    float* __restrict__ kv_g, float* __restrict__ ks_g) {

    __shared__ __align__(16) float kt[32*68];
    __shared__ __align__(16) float vt[32*68];

    const int t = threadIdx.x;
    const int g = blockIdx.x;       // 0..6 (n-groups of 448)
    const int h = blockIdx.y;
    const int b = blockIdx.z;
    const int e = t & 31, dbase = t >> 5;   // 0..7

    const float* kb = k_ws + ((long long)(b*GCn + h*32))*HWn;
    const float* vb = x    + ((long long)(b*Cn + GCn + h*32))*HWn;

    float s[4] = {0.f,0.f,0.f,0.f};
    float ksm = 0.f;

    for (int ch = 0; ch < 7; ++ch) {
        const int n0 = g*448 + ch*64;
        #pragma unroll
        for (int l = 0; l < 2; ++l) {
            int idx4 = t + l*256;
            int d = idx4 >> 4, j4 = idx4 & 15;
            *(float4*)(kt + d*68 + j4*4) = *(const float4*)(kb + (long long)d*HWn + n0 + j4*4);
            *(float4*)(vt + d*68 + j4*4) = *(const float4*)(vb + (long long)d*HWn + n0 + j4*4);
        }
        __syncthreads();
        #pragma unroll
        for (int j4 = 0; j4 < 16; ++j4) {
            const float4 vv = *(const float4*)(vt + e*68 + j4*4);
            #pragma unroll
            for (int r = 0; r < 4; ++r) {
                const float4 kk = *(const float4*)(kt + (dbase + 8*r)*68 + j4*4);
                s[r] += kk.x*vv.x + kk.y*vv.y + kk.z*vv.z + kk.w*vv.w;
            }
        }
        if (t < 32) {
            #pragma unroll
            for (int j = 0; j < 64; ++j) ksm += kt[t*68 + j];
        }
        __syncthreads();
    }
    const int bh = b*4 + h;
    #pragma unroll
    for (int r = 0; r < 4; ++r)
        atomicAdd(&kv_g[(bh << 10) + (dbase + 8*r)*32 + e], s[r]);
    if (t < 32) atomicAdd(&ks_g[bh*32 + t], ksm);
}

// ---- att epilogue: att[n,e] = (sum_d q[n,d]*kv[d,e]) / (q[n,:].kmean + 1e-6) ----
__global__ __launch_bounds__(256) void k_att(
    const float* __restrict__ q_ws, const float* __restrict__ kv_g,
    const float* __restrict__ ks_g, float* __restrict__ feats) {

    __shared__ float kvl[1024];
    __shared__ float kml[32];
    const int t = threadIdx.x;
    const int h = blockIdx.y, b = blockIdx.z;
    const int bh = b*4 + h;
    const float inv = 1.0f / 3136.0f;
    #pragma unroll
    for (int l = 0; l < 4; ++l) kvl[t + l*256] = kv_g[(bh << 10) + t + l*256] * inv;
    if (t < 32) kml[t] = ks_g[bh*32 + t] * inv;
    __syncthreads();

    const int n = blockIdx.x * 256 + t;
    if (n >= HWn) return;
    const float* qp = q_ws + ((long long)(b*GCn + h*32))*HWn + n;
    float accv[32];
    #pragma unroll
    for (int e = 0; e < 32; ++e) accv[e] = 0.f;
    float zden = 1e-6f;
    #pragma unroll 8
    for (int d = 0; d < 32; ++d) {
        const float qd = qp[(long long)d * HWn];
        zden = __builtin_fmaf(qd, kml[d], zden);
        #pragma unroll
        for (int e = 0; e < 32; ++e)
            accv[e] = __builtin_fmaf(qd, kvl[d*32 + e], accv[e]);
    }
    const float z = 1.0f / zden;
    float* opp = feats + ((long long)(b*384 + h*32))*HWn + n;
    #pragma unroll
    for (int e = 0; e < 32; ++e) opp[(long long)e*HWn] = accv[e] * z;
}

// ---- depthwise conv, register-blocked 4-wide, aligned float4 loads ----
template<int KS, int PAD, int CIN, int COUT>
__global__ __launch_bounds__(256) void k_dwconv(
    const float* __restrict__ x, const float* __restrict__ wg,
    const float* __restrict__ bg, float* __restrict__ feats) {

    const int c = blockIdx.x, b = blockIdx.y;
    const float* in = x + ((long long)(b*Cn + CIN + c))*HWn;
    float* op = feats + ((long long)(b*384 + COUT + c))*HWn;

    float wr[KS*KS];
    #pragma unroll
    for (int i = 0; i < KS*KS; ++i) wr[i] = wg[c*KS*KS + i];
    const float bias = bg[c];

    for (int item = threadIdx.x; item < 784; item += 256) {
        const int y  = item / 14;
        const int xq = (item % 14) * 4;
        float acc[4] = {bias, bias, bias, bias};
        #pragma unroll
        for (int dy = 0; dy < KS; ++dy) {
            const int yy = y + dy - PAD;
            if (yy < 0 || yy >= 56) continue;
            const float* row = in + yy*56 + xq;
            float r[12];
            float4 f;
            if (xq >= 4) f = *(const float4*)(row - 4); else f = make_float4(0,0,0,0);
            r[0]=f.x; r[1]=f.y; r[2]=f.z; r[3]=f.w;
            f = *(const float4*)(row);
            r[4]=f.x; r[5]=f.y; r[6]=f.z; r[7]=f.w;
            if (xq <= 48) f = *(const float4*)(row + 4); else f = make_float4(0,0,0,0);
            r[8]=f.x; r[9]=f.y; r[10]=f.z; r[11]=f.w;
            #pragma unroll
            for (int dx = 0; dx < KS; ++dx) {
                const float wv = wr[dy*KS + dx];
                #pragma unroll
                for (int j = 0; j < 4; ++j)
                    acc[j] = __builtin_fmaf(wv, r[j + dx + 4 - PAD], acc[j]);
            }
        }
        *(float4*)(op + y*56 + xq) = make_float4(acc[0], acc[1], acc[2], acc[3]);
    }
}

extern "C" void kernel_launch(void* const* d_in, const int* in_sizes, int n_in,
                              void* d_out, int out_size, void* d_ws, size_t ws_size,
                              hipStream_t stream) {
    const float* x     = (const float*)d_in[0];
    const float* w_dw1 = (const float*)d_in[1];
    const float* b_dw1 = (const float*)d_in[2];
    const float* w_dw2 = (const float*)d_in[3];
    const float* b_dw2 = (const float*)d_in[4];
    const float* w_qk  = (const float*)d_in[5];
    const float* b_qk  = (const float*)d_in[6];
    float* out = (float*)d_out;
    float* ws  = (float*)d_ws;

    // workspace layout (floats): q | k | kv | ksum | wt   (~103.4 MB total)
    float* q_ws = ws;
    float* k_ws = ws + (long long)Q_ELEMS;
    float* kv_g = ws + 2LL*Q_ELEMS;
    float* ks_g = kv_g + KV_ELEMS;
    float* wt_g = ks_g + KS_ELEMS;

    float* mem_out = out;
    float* feats   = out + (long long)Bn*GCn*HWn;

    hipMemsetAsync(kv_g, 0, (KV_ELEMS + KS_ELEMS)*sizeof(float), stream);
    k_wt  <<<128, 256, 0, stream>>>(w_qk, wt_g);
    k_copy<<<12544, 256, 0, stream>>>(x, mem_out);
    k_qkgemm<<<dim3(49, 32), 256, 0, stream>>>(x, wt_g, b_qk, q_ws, k_ws);
    k_kv  <<<dim3(7, 4, 32), 256, 0, stream>>>(x, k_ws, kv_g, ks_g);
    k_att <<<dim3(13, 4, 32), 256, 0, stream>>>(q_ws, kv_g, ks_g, feats);
    k_dwconv<3,1,256,128><<<dim3(128,32), 256, 0, stream>>>(x, w_dw1, b_dw1, feats);
    k_dwconv<7,3,384,256><<<dim3(128,32), 256, 0, stream>>>(x, w_dw2, b_dw2, feats);
}

// Round 2
// 492.863 us; speedup vs baseline: 1.2139x; 1.2139x over previous
//
#include <hip/hip_runtime.h>
#include <hip/hip_bf16.h>

#define Bn   32
#define Cn   512
#define GCn  128
#define HWn  3136
#define M0   128

#define Q_ELEMS  (Bn*GCn*HWn)     // 12845056 (bf16 elems)
#define KV_ELEMS (Bn*4*32*32)     // 131072
#define KS_ELEMS (Bn*4*32)        // 4096

typedef __attribute__((ext_vector_type(8))) short bf16x8;
typedef __attribute__((ext_vector_type(4))) float f32x4;

__device__ __forceinline__ float bf2f(unsigned short u) {
    union { unsigned int i; float f; } v; v.i = ((unsigned int)u) << 16; return v.f;
}
__device__ __forceinline__ unsigned short f2bf(float f) {
    union { __hip_bfloat16 h; unsigned short u; } v; v.h = __float2bfloat16(f); return v.u;
}
__device__ __forceinline__ float act_elu1(float v) {
    return v > 0.0f ? v + 1.0f : __expf(v);
}

// ---- pre-swizzle w_qk (256x128 fp32) into bf16 A-fragment order ----
// wfrag[((mt*4+ks)*64 + lane)*8 + j] = W[o=16mt+(lane&15)][c=32ks+8*(lane>>4)+j]
__global__ void k_wt(const float* __restrict__ w_qk, unsigned short* __restrict__ wfrag) {
    int idx = blockIdx.x * 256 + threadIdx.x;    // 32768
    int j  = idx & 7;
    int l  = (idx >> 3) & 63;
    int ks = (idx >> 9) & 3;
    int mt = idx >> 11;
    int o = mt * 16 + (l & 15);
    int c = ks * 32 + (l >> 4) * 8 + j;
    wfrag[idx] = f2bf(w_qk[o * 128 + c]);
}

// ---- mem = x[:, :128] copy, float4 ----
__global__ void k_copy(const float* __restrict__ x, float* __restrict__ out) {
    long long idx4 = (long long)blockIdx.x * 256 + threadIdx.x;  // < 3211264
    int b = (int)(idx4 / 100352);
    int r = (int)(idx4 % 100352);
    ((float4*)out)[idx4] = ((const float4*)x)[(long long)b * 401408 + r];
}

// ---- qk 1x1-conv via MFMA: block = 256o x 64n, K=128. writes elu(qk)+1 as bf16 ----
__global__ __launch_bounds__(256) void k_qkgemm(
    const float* __restrict__ x, const unsigned short* __restrict__ wfrag,
    const float* __restrict__ b_qk,
    unsigned short* __restrict__ q_ws, unsigned short* __restrict__ k_ws) {

    __shared__ float Xl[128 * 66];   // [c][n], stride 66 -> transpose-reads 2-way (free)

    const int t  = threadIdx.x;
    const int n0 = blockIdx.x * 64;
    const int b  = blockIdx.y;
    const float* xa = x + ((long long)(b * Cn + M0)) * HWn;

    #pragma unroll
    for (int p = 0; p < 8; ++p) {                 // stage 128c x 64n fp32
        int idx4 = p * 256 + t;
        int c = idx4 >> 4, j4 = idx4 & 15;
        float4 v = *(const float4*)(xa + (long long)c * HWn + n0 + j4 * 4);
        float* d = Xl + c * 66 + j4 * 4;
        *(float2*)(d)     = make_float2(v.x, v.y);
        *(float2*)(d + 2) = make_float2(v.z, v.w);
    }
    __syncthreads();

    const int w = t >> 6, l = t & 63, nn = l & 15, q = l >> 4;
    f32x4 acc[4][4] = {};     // [im][in]

    #pragma unroll
    for (int ks = 0; ks < 4; ++ks) {
        bf16x8 bq[4];
        #pragma unroll
        for (int in = 0; in < 4; ++in) {
            const float* src = Xl + (ks * 32 + q * 8) * 66 + in * 16 + nn;
            short tmp[8];
            #pragma unroll
            for (int j = 0; j < 8; ++j) tmp[j] = (short)f2bf(src[j * 66]);
            bq[in] = *(bf16x8*)tmp;
        }
        #pragma unroll
        for (int im = 0; im < 4; ++im) {
            const int mt = 4 * w + im;
            bf16x8 aq = *(const bf16x8*)(wfrag + ((mt * 4 + ks) * 64 + l) * 8);
            #pragma unroll
            for (int in = 0; in < 4; ++in)
                acc[im][in] = __builtin_amdgcn_mfma_f32_16x16x32_bf16(aq, bq[in], acc[im][in], 0, 0, 0);
        }
    }

    #pragma unroll
    for (int im = 0; im < 4; ++im) {
        const int obase = w * 64 + im * 16 + q * 4;   // + r
        float4 bias4 = *(const float4*)(b_qk + obase);
        unsigned short* dst_ws = (w < 2) ? q_ws : k_ws;
        const int orow = obase & 127;
        #pragma unroll
        for (int r = 0; r < 4; ++r) {
            const float bias = ((const float*)&bias4)[r];
            unsigned short* dst = dst_ws + ((long long)(b * GCn + orow + r)) * HWn + n0 + nn;
            #pragma unroll
            for (int in = 0; in < 4; ++in)
                dst[in * 16] = f2bf(act_elu1(acc[im][in][r] + bias));
        }
    }
}

// ---- kv[d][e] + ksum[d] via MFMA, direct-from-global frags, atomic combine ----
__global__ __launch_bounds__(256) void k_kv(
    const float* __restrict__ x, const unsigned short* __restrict__ k_ws,
    float* __restrict__ kv_g, float* __restrict__ ks_g) {

    const int t = threadIdx.x, w = t >> 6, l = t & 63, nn = l & 15, q = l >> 4;
    const int g = blockIdx.x, h = blockIdx.y, b = blockIdx.z;
    const int dm = w >> 1, en = w & 1;
    const int d = h * 32 + dm * 16 + nn;
    const int e = h * 32 + en * 16 + nn;
    const unsigned short* kp = k_ws + ((long long)(b * GCn + d)) * HWn;
    const float* vp = x + ((long long)(b * Cn + M0 + e)) * HWn;

    f32x4 acc = {};
    float ksl = 0.f;
    for (int ks = 0; ks < 14; ++ks) {
        const int n = g * 448 + ks * 32 + q * 8;
        bf16x8 aq = *(const bf16x8*)(kp + n);
        float4 v0 = *(const float4*)(vp + n);
        float4 v1 = *(const float4*)(vp + n + 4);
        short tb[8];
        tb[0] = (short)f2bf(v0.x); tb[1] = (short)f2bf(v0.y);
        tb[2] = (short)f2bf(v0.z); tb[3] = (short)f2bf(v0.w);
        tb[4] = (short)f2bf(v1.x); tb[5] = (short)f2bf(v1.y);
        tb[6] = (short)f2bf(v1.z); tb[7] = (short)f2bf(v1.w);
        bf16x8 bq = *(bf16x8*)tb;
        acc = __builtin_amdgcn_mfma_f32_16x16x32_bf16(aq, bq, acc, 0, 0, 0);
        if (en == 0) {
            const unsigned short* au = (const unsigned short*)&aq;
            #pragma unroll
            for (int j = 0; j < 8; ++j) ksl += bf2f(au[j]);
        }
    }
    const int bh = b * 4 + h;
    #pragma unroll
    for (int r = 0; r < 4; ++r)
        atomicAdd(&kv_g[(bh << 10) + (dm * 16 + q * 4 + r) * 32 + en * 16 + nn], acc[r]);
    if (en == 0) atomicAdd(&ks_g[bh * 32 + dm * 16 + nn], ksl);
}

// ---- att epilogue: 2 pixels/thread, q bf16, kv broadcast from LDS ----
__global__ __launch_bounds__(256) void k_att(
    const unsigned short* __restrict__ q_ws, const float* __restrict__ kv_g,
    const float* __restrict__ ks_g, float* __restrict__ feats) {

    __shared__ float kvl[1024];
    __shared__ float kml[32];
    const int t = threadIdx.x, h = blockIdx.y, b = blockIdx.z;
    const int bh = b * 4 + h;
    const float inv = 1.0f / 3136.0f;
    #pragma unroll
    for (int p = 0; p < 4; ++p) kvl[t + p * 256] = kv_g[(bh << 10) + t + p * 256] * inv;
    if (t < 32) kml[t] = ks_g[bh * 32 + t] * inv;
    __syncthreads();

    const int n2 = blockIdx.x * 256 + t;
    if (n2 >= 1568) return;
    const unsigned short* qp = q_ws + ((long long)(b * GCn + h * 32)) * HWn + n2 * 2;
    float a0[32], a1[32];
    float z0 = 1e-6f, z1 = 1e-6f;
    #pragma unroll
    for (int e = 0; e < 32; ++e) { a0[e] = 0.f; a1[e] = 0.f; }
    #pragma unroll 4
    for (int d = 0; d < 32; ++d) {
        const unsigned int qq = *(const unsigned int*)(qp + (long long)d * HWn);
        const float q0 = bf2f((unsigned short)qq);
        const float q1 = bf2f((unsigned short)(qq >> 16));
        z0 = __builtin_fmaf(q0, kml[d], z0);
        z1 = __builtin_fmaf(q1, kml[d], z1);
        #pragma unroll
        for (int e = 0; e < 32; ++e) {
            const float kv = kvl[d * 32 + e];
            a0[e] = __builtin_fmaf(q0, kv, a0[e]);
            a1[e] = __builtin_fmaf(q1, kv, a1[e]);
        }
    }
    z0 = 1.f / z0; z1 = 1.f / z1;
    float* op = feats + ((long long)(b * 384 + h * 32)) * HWn + n2 * 2;
    #pragma unroll
    for (int e = 0; e < 32; ++e)
        *(float2*)(op + (long long)e * HWn) = make_float2(a0[e] * z0, a1[e] * z1);
}

// ---- depthwise conv, register-blocked 4-wide, aligned float4 loads ----
template<int KS, int PAD, int CIN, int COUT>
__global__ __launch_bounds__(256) void k_dwconv(
    const float* __restrict__ x, const float* __restrict__ wg,
    const float* __restrict__ bg, float* __restrict__ feats) {

    const int c = blockIdx.x, b = blockIdx.y;
    const float* in = x + ((long long)(b * Cn + CIN + c)) * HWn;
    float* op = feats + ((long long)(b * 384 + COUT + c)) * HWn;

    float wr[KS * KS];
    #pragma unroll
    for (int i = 0; i < KS * KS; ++i) wr[i] = wg[c * KS * KS + i];
    const float bias = bg[c];

    for (int item = threadIdx.x; item < 784; item += 256) {
        const int y  = item / 14;
        const int xq = (item % 14) * 4;
        float acc[4] = {bias, bias, bias, bias};
        #pragma unroll
        for (int dy = 0; dy < KS; ++dy) {
            const int yy = y + dy - PAD;
            if (yy < 0 || yy >= 56) continue;
            const float* row = in + yy * 56 + xq;
            float r[12];
            float4 f;
            if (xq >= 4) f = *(const float4*)(row - 4); else f = make_float4(0, 0, 0, 0);
            r[0] = f.x; r[1] = f.y; r[2] = f.z; r[3] = f.w;
            f = *(const float4*)(row);
            r[4] = f.x; r[5] = f.y; r[6] = f.z; r[7] = f.w;
            if (xq <= 48) f = *(const float4*)(row + 4); else f = make_float4(0, 0, 0, 0);
            r[8] = f.x; r[9] = f.y; r[10] = f.z; r[11] = f.w;
            #pragma unroll
            for (int dx = 0; dx < KS; ++dx) {
                const float wv = wr[dy * KS + dx];
                #pragma unroll
                for (int j = 0; j < 4; ++j)
                    acc[j] = __builtin_fmaf(wv, r[j + dx + 4 - PAD], acc[j]);
            }
        }
        *(float4*)(op + y * 56 + xq) = make_float4(acc[0], acc[1], acc[2], acc[3]);
    }
}

extern "C" void kernel_launch(void* const* d_in, const int* in_sizes, int n_in,
                              void* d_out, int out_size, void* d_ws, size_t ws_size,
                              hipStream_t stream) {
    const float* x     = (const float*)d_in[0];
    const float* w_dw1 = (const float*)d_in[1];
    const float* b_dw1 = (const float*)d_in[2];
    const float* w_dw2 = (const float*)d_in[3];
    const float* b_dw2 = (const float*)d_in[4];
    const float* w_qk  = (const float*)d_in[5];
    const float* b_qk  = (const float*)d_in[6];
    float* out = (float*)d_out;

    // ws layout: q bf16 | k bf16 | kv f32 | ksum f32 | wfrag bf16  (~52.5 MB)
    unsigned short* q_ws = (unsigned short*)d_ws;
    unsigned short* k_ws = q_ws + (long long)Q_ELEMS;
    float* kv_g = (float*)(k_ws + (long long)Q_ELEMS);
    float* ks_g = kv_g + KV_ELEMS;
    unsigned short* wfrag = (unsigned short*)(ks_g + KS_ELEMS);

    float* mem_out = out;
    float* feats   = out + (long long)Bn * GCn * HWn;

    hipMemsetAsync(kv_g, 0, (KV_ELEMS + KS_ELEMS) * sizeof(float), stream);
    k_wt  <<<128, 256, 0, stream>>>(w_qk, wfrag);
    k_copy<<<12544, 256, 0, stream>>>(x, mem_out);
    k_qkgemm<<<dim3(49, 32), 256, 0, stream>>>(x, wfrag, b_qk, q_ws, k_ws);
    k_kv  <<<dim3(7, 4, 32), 256, 0, stream>>>(x, k_ws, kv_g, ks_g);
    k_att <<<dim3(7, 4, 32), 256, 0, stream>>>(q_ws, kv_g, ks_g, feats);
    k_dwconv<3, 1, 256, 128><<<dim3(128, 32), 256, 0, stream>>>(x, w_dw1, b_dw1, feats);
    k_dwconv<7, 3, 384, 256><<<dim3(128, 32), 256, 0, stream>>>(x, w_dw2, b_dw2, feats);
}